// Round 7
// baseline (348.288 us; speedup 1.0000x reference)
//
#include <hip/hip_runtime.h>
#include <stdint.h>

// Problem constants (B=64, N=197)
#define M_TOK 12608      // 64*197 tokens
#define MPAD  12672      // 198 * 64
#define CIN   768
#define CD    256
#define NE    8192
#define NCHUNK 8
#define CHUNK  1024

typedef unsigned long long u64;
typedef unsigned int u32;
typedef _Float16 f16;
typedef _Float16 f16x8 __attribute__((ext_vector_type(8)));
typedef _Float16 f16x4 __attribute__((ext_vector_type(4)));
typedef float f32x4 __attribute__((ext_vector_type(4)));

#if __has_builtin(__builtin_amdgcn_global_load_lds)
#define HAVE_GLL 1
#else
#define HAVE_GLL 0
#endif

// Stage one 16B chunk per lane into LDS. lds_base is wave-uniform; HW (or the
// fallback) adds lane*16.
__device__ __forceinline__ void stage16(const f16* src, char* lds_base, int lane)
{
#if HAVE_GLL
    __builtin_amdgcn_global_load_lds(
        (__attribute__((address_space(1))) void*)(src),
        (__attribute__((address_space(3))) void*)(lds_base), 16, 0, 0);
#else
    *(f16x8*)(lds_base + lane * 16) = *(const f16x8*)src;
#endif
}

// ---------------------------------------------------------------------------
// Fused prep: region A (2048 blocks): enorm + embf16 + loss zero.
// Region B (768 blocks): weight prep (WcT hi/lo split, WeT f16).
// Region C (9456 blocks): z -> zhi + zlo split.
__global__ __launch_bounds__(256) void k_prep(const float* __restrict__ emb,
                                              const float* __restrict__ Wc,
                                              const float* __restrict__ We,
                                              const float* __restrict__ z,
                                              float* __restrict__ enorm,
                                              f16* __restrict__ embf16,
                                              f16* __restrict__ wchi,
                                              f16* __restrict__ wclo,
                                              f16* __restrict__ wet,
                                              f16* __restrict__ zhi,
                                              f16* __restrict__ zlo,
                                              float* __restrict__ loss_slot)
{
    const int b = blockIdx.x;
    const int t = threadIdx.x;
    if (b < 2048) {
        if (b == 0 && t == 0) *loss_slot = 0.0f;
        int row  = b * 4 + (t >> 6);
        int lane = t & 63;
        float4 v = *(const float4*)&emb[(size_t)row * CD + lane * 4];
        f16x4 hv = { (f16)v.x, (f16)v.y, (f16)v.z, (f16)v.w };
        *(f16x4*)&embf16[(size_t)row * CD + lane * 4] = hv;
        float s = v.x*v.x + v.y*v.y + v.z*v.z + v.w*v.w;
        #pragma unroll
        for (int o = 32; o; o >>= 1) s += __shfl_down(s, o, 64);
        if (lane == 0) enorm[row] = s;
    } else if (b < 2048 + 768) {
        int tid = (b - 2048) * 256 + t;            // < 196608
        {
            int n = tid & 255, k = tid >> 8;
            float v = Wc[(size_t)k * CD + n];
            f16 h = (f16)v;
            wchi[(size_t)n * CIN + k] = h;
            wclo[(size_t)n * CIN + k] = (f16)(v - (float)h);
        }
        {
            int d = tid / CIN, c = tid - d * CIN;
            wet[(size_t)c * CD + d] = (f16)We[(size_t)d * CIN + c];
        }
    } else {
        size_t i4 = (size_t)(b - 2816) * 256 + t;  // float4 idx, 2420736 total
        float4 v = ((const float4*)z)[i4];
        f16x4 h = { (f16)v.x, (f16)v.y, (f16)v.z, (f16)v.w };
        f16x4 lo = { (f16)(v.x - (float)h.x), (f16)(v.y - (float)h.y),
                     (f16)(v.z - (float)h.z), (f16)(v.w - (float)h.w) };
        ((f16x4*)zhi)[i4] = h;
        ((f16x4*)zlo)[i4] = lo;
    }
}

// ---------------------------------------------------------------------------
// Fused split-f16 compress: zc = zhi@WhiT + zhi@WloT + zlo@WhiT + bc, writes
// zc (f32) and zcf16. 128x64 tile, BK=64, K=768.
__global__ __launch_bounds__(256) void k_compress_f(const f16* __restrict__ zhi,
                                                    const f16* __restrict__ zlo,
                                                    const f16* __restrict__ wchi,
                                                    const f16* __restrict__ wclo,
                                                    const float* __restrict__ bc,
                                                    float* __restrict__ zc,
                                                    f16* __restrict__ zcf16)
{
    __shared__ __align__(16) f16 Ah[128 * 64];   // 16 KB
    __shared__ __align__(16) f16 Al[128 * 64];   // 16 KB
    __shared__ __align__(16) f16 Bh[64 * 64];    // 8 KB
    __shared__ __align__(16) f16 Bl[64 * 64];    // 8 KB

    const int t = threadIdx.x;
    const int w = t >> 6, l = t & 63;
    const int wrow = w * 32;
    const int m0   = blockIdx.x * 128;
    const int col0 = blockIdx.y * 64;

    const int cg   = (t & 7) ^ ((t >> 3) & 7);
    const int rloc = t >> 3;
    const f16* ahsrc[4]; const f16* alsrc[4];
    #pragma unroll
    for (int i = 0; i < 4; ++i) {
        int am = m0 + i * 32 + rloc; am = am < M_TOK ? am : (M_TOK - 1);
        ahsrc[i] = zhi + (size_t)am * CIN + cg * 8;
        alsrc[i] = zlo + (size_t)am * CIN + cg * 8;
    }
    const f16* bhsrc[2]; const f16* blsrc[2];
    #pragma unroll
    for (int i = 0; i < 2; ++i) {
        int br = col0 + i * 32 + rloc;
        bhsrc[i] = wchi + (size_t)br * CIN + cg * 8;
        blsrc[i] = wclo + (size_t)br * CIN + cg * 8;
    }

    f32x4 acc[2][4];
    #pragma unroll
    for (int a = 0; a < 2; ++a)
        #pragma unroll
        for (int b2 = 0; b2 < 4; ++b2) acc[a][b2] = (f32x4){0.f,0.f,0.f,0.f};

    for (int ks = 0; ks < CIN / 64; ++ks) {
        __syncthreads();
        #pragma unroll
        for (int i = 0; i < 4; ++i) {
            stage16(ahsrc[i] + ks * 64, (char*)Ah + (i * 256 + w * 64) * 16, l);
            stage16(alsrc[i] + ks * 64, (char*)Al + (i * 256 + w * 64) * 16, l);
        }
        #pragma unroll
        for (int i = 0; i < 2; ++i) {
            stage16(bhsrc[i] + ks * 64, (char*)Bh + (i * 256 + w * 64) * 16, l);
            stage16(blsrc[i] + ks * 64, (char*)Bl + (i * 256 + w * 64) * 16, l);
        }
        __syncthreads();
        #pragma unroll
        for (int kk = 0; kk < 2; ++kk) {
            const int pofs = ((kk * 4 + (l >> 4)) ^ (l & 7)) * 16;
            f16x8 ah[2], al[2], bh[4], bl[4];
            #pragma unroll
            for (int tm = 0; tm < 2; ++tm) {
                ah[tm] = *(const f16x8*)((const char*)Ah + (wrow + tm*16 + (l & 15)) * 128 + pofs);
                al[tm] = *(const f16x8*)((const char*)Al + (wrow + tm*16 + (l & 15)) * 128 + pofs);
            }
            #pragma unroll
            for (int tn = 0; tn < 4; ++tn) {
                bh[tn] = *(const f16x8*)((const char*)Bh + (tn*16 + (l & 15)) * 128 + pofs);
                bl[tn] = *(const f16x8*)((const char*)Bl + (tn*16 + (l & 15)) * 128 + pofs);
            }
            #pragma unroll
            for (int tm = 0; tm < 2; ++tm)
                #pragma unroll
                for (int tn = 0; tn < 4; ++tn) {
                    f32x4 a = acc[tm][tn];
                    a = __builtin_amdgcn_mfma_f32_16x16x32_f16(ah[tm], bh[tn], a, 0, 0, 0);
                    a = __builtin_amdgcn_mfma_f32_16x16x32_f16(ah[tm], bl[tn], a, 0, 0, 0);
                    a = __builtin_amdgcn_mfma_f32_16x16x32_f16(al[tm], bh[tn], a, 0, 0, 0);
                    acc[tm][tn] = a;
                }
        }
    }

    #pragma unroll
    for (int tm = 0; tm < 2; ++tm) {
        #pragma unroll
        for (int reg = 0; reg < 4; ++reg) {
            int row = m0 + wrow + tm * 16 + (l >> 4) * 4 + reg;
            if (row < M_TOK) {
                #pragma unroll
                for (int tn = 0; tn < 4; ++tn) {
                    int col = col0 + tn * 16 + (l & 15);
                    float v = acc[tm][tn][reg] + bc[col];
                    zc[(size_t)row * CD + col] = v;
                    zcf16[(size_t)row * CD + col] = (f16)v;
                }
            }
        }
    }
}

// ---------------------------------------------------------------------------
// Coarse distance GEMM v5: barrier-free K-loop. A (64 rows x 256K) bounced
// global->LDS->AGPRs once (asm memory-clobber pins residency); B fragments
// loaded per-wave DIRECTLY from global (L2-hot, cacheline-aligned pattern:
// 4 lanes x 16B per codeword row), one-tile software prefetch. No LDS and no
// __syncthreads in the j-loop -> no barrier-drain stalls.
__global__ __launch_bounds__(256, 2) void k_dist_mfma(const f16* __restrict__ zcf16,
                                                      const f16* __restrict__ embf16,
                                                      const float* __restrict__ enorm,
                                                      u64* __restrict__ part)
{
    __shared__ __align__(16) f16 Abuf[64 * 256];  // 32 KB bounce buffer
    __shared__ u64 wred[64][4][2];                // 4 KB

    const int t = threadIdx.x;
    const int w = t >> 6, l = t & 63;
    const int m0    = blockIdx.x * 64;            // 198 m-blocks
    const int chunk = blockIdx.y;                 // 0..7
    const int jb    = chunk * CHUNK + w * 256;    // wave's 256-col range

    // ---- stage A (swizzled) and extract to registers (AGPR-resident) ----
    #pragma unroll
    for (int i = 0; i < 8; ++i) {
        int r = (w * 8 + i) * 2 + (l >> 5);
        int c = (l & 31) ^ (r & 7);
        int gr = m0 + r; gr = gr < M_TOK ? gr : (M_TOK - 1);
        stage16(zcf16 + (size_t)gr * CD + c * 8, (char*)Abuf + (w * 8 + i) * 1024, l);
    }
    __syncthreads();
    f16x8 afr[4][8];
    #pragma unroll
    for (int mb = 0; mb < 4; ++mb) {
        int rl = mb * 16 + (l & 15);
        #pragma unroll
        for (int ks = 0; ks < 8; ++ks) {
            int pc = (ks * 4 + (l >> 4)) ^ (rl & 7);
            afr[mb][ks] = *(const f16x8*)((const char*)Abuf + rl * 512 + pc * 16);
        }
    }
    // Pin afr in registers: reads may not sink/remat past a memory clobber.
    asm volatile("" ::: "memory");

    float bd[16];
    #pragma unroll
    for (int s = 0; s < 16; ++s) bd[s] = __builtin_inff();

    // ---- barrier-free j-loop: 16 tiles of 16 cols, B direct from global ----
    const f16* bpbase = embf16 + (size_t)(jb + (l & 15)) * CD + (l >> 4) * 8;
    f16x8 bf[8];
    #pragma unroll
    for (int ks = 0; ks < 8; ++ks) bf[ks] = *(const f16x8*)(bpbase + ks * 32);

    for (int jt = 0; jt < 16; ++jt) {
        // prefetch next tile's fragments (wraps harmlessly at the end)
        f16x8 bfn[8];
        const f16* bpn = bpbase + (size_t)(((jt + 1) & 15) * 16) * CD;
        #pragma unroll
        for (int ks = 0; ks < 8; ++ks) bfn[ks] = *(const f16x8*)(bpn + ks * 32);

        f32x4 acc[4];
        #pragma unroll
        for (int mb = 0; mb < 4; ++mb) acc[mb] = (f32x4){0.f,0.f,0.f,0.f};
        #pragma unroll
        for (int ks = 0; ks < 8; ++ks)
            #pragma unroll
            for (int mb = 0; mb < 4; ++mb)
                acc[mb] = __builtin_amdgcn_mfma_f32_16x16x32_f16(afr[mb][ks], bf[ks], acc[mb], 0, 0, 0);

        float en = enorm[jb + jt * 16 + (l & 15)];
        #pragma unroll
        for (int mb = 0; mb < 4; ++mb) {
            #pragma unroll
            for (int reg = 0; reg < 4; ++reg) {
                float d = fmaf(acc[mb][reg], -2.f, en);
                float ds = __uint_as_float((__float_as_uint(d) & ~15u) | (u32)jt);
                float cur = bd[mb * 4 + reg];
                bd[mb * 4 + reg] = ds < cur ? ds : cur;
            }
        }
        #pragma unroll
        for (int ks = 0; ks < 8; ++ks) bf[ks] = bfn[ks];
    }

    // ---- per-row top-2 across the 16 col-lanes, merge 4 waves in LDS ----
    #pragma unroll
    for (int mb = 0; mb < 4; ++mb) {
        #pragma unroll
        for (int reg = 0; reg < 4; ++reg) {
            u32 bits = __float_as_uint(bd[mb * 4 + reg]);
            int jtb  = (int)(bits & 15u);
            int col  = jb + jtb * 16 + (l & 15);
            u32 u = (bits & 0x80000000u) ? ~bits : (bits | 0x80000000u);
            u64 b  = ((u64)u << 32) | (u32)col;
            u64 s2 = ~0ull;
            #pragma unroll
            for (int off = 1; off <= 8; off <<= 1) {
                u64 ob = __shfl_xor(b, off, 64);
                u64 os = __shfl_xor(s2, off, 64);
                u64 nb = b < ob ? b : ob;
                u64 mx = b < ob ? ob : b;
                s2 = s2 < os ? s2 : os;
                s2 = s2 < mx ? s2 : mx;
                b = nb;
            }
            if ((l & 15) == 0) {
                int row = mb * 16 + (l >> 4) * 4 + reg;
                wred[row][w][0] = b;
                wred[row][w][1] = s2;
            }
        }
    }
    __syncthreads();
    if (t < 64) {
        u64 best = wred[t][0][0], sec = wred[t][0][1];
        #pragma unroll
        for (int c = 1; c < 4; ++c) {
            u64 b = wred[t][c][0], s = wred[t][c][1];
            if (b < best) { sec = (best < s) ? best : s; best = b; }
            else if (b < sec) { sec = b; }
        }
        int row = m0 + t;
        if (row < M_TOK) {
            part[((size_t)row * NCHUNK + chunk) * 2 + 0] = best;
            part[((size_t)row * NCHUNK + chunk) * 2 + 1] = sec;
        }
    }
}

// ---------------------------------------------------------------------------
// Exact fp32 rescore: candidate = lane&15, K-quarter = lane>>4 (parallel dots,
// no serial candidate loop). Fused loss. One wave per row, 4 rows/block.
__global__ __launch_bounds__(256) void k_rescore(const float* __restrict__ zc,
                                                 const float* __restrict__ emb,
                                                 const float* __restrict__ enorm,
                                                 const u64* __restrict__ part,
                                                 int* __restrict__ idxp,
                                                 float* __restrict__ loss_slot)
{
    const int row = blockIdx.x * 4 + (threadIdx.x >> 6);   // grid 3152 -> exactly M_TOK
    const int l   = threadIdx.x & 63;
    const int c   = l & 15;       // candidate
    const int q   = l >> 4;       // K-quarter (64 elems)
    __shared__ float lsum[4];

    u64 key = part[(size_t)row * 16 + c];
    int col = (int)((u32)key & (NE - 1));
    const float4* ep = (const float4*)emb + (size_t)col * 64 + q * 16;
    const float4* zp = (const float4*)zc  + (size_t)row * 64 + q * 16;

    float p = 0.f, zn = 0.f;
    #pragma unroll
    for (int i = 0; i < 16; ++i) {
        float4 e = ep[i], zv = zp[i];
        p  = fmaf(e.x, zv.x, fmaf(e.y, zv.y, fmaf(e.z, zv.z, fmaf(e.w, zv.w, p))));
        zn = fmaf(zv.x, zv.x, fmaf(zv.y, zv.y, fmaf(zv.z, zv.z, fmaf(zv.w, zv.w, zn))));
    }
    p  += __shfl_xor(p, 16, 64);  p  += __shfl_xor(p, 32, 64);
    zn += __shfl_xor(zn, 16, 64); zn += __shfl_xor(zn, 32, 64);

    float d = fmaf(p, -2.f, enorm[col]);
    u32 u = __float_as_uint(d);
    u = (u & 0x80000000u) ? ~u : (u | 0x80000000u);
    u64 best = ((u64)u << 32) | (u32)col;
    #pragma unroll
    for (int off = 1; off <= 8; off <<= 1) {
        u64 ob = __shfl_xor(best, off, 64);
        best = ob < best ? ob : best;
    }

    u32 hi = (u32)(best >> 32);
    float dbest = (hi & 0x80000000u) ? __uint_as_float(hi & 0x7fffffffu)
                                     : __uint_as_float(~hi);
    if (l == 0) {
        idxp[row] = (int)((u32)best & (NE - 1));
        lsum[threadIdx.x >> 6] = dbest + zn;
    }
    __syncthreads();
    if (threadIdx.x == 0) {
        float tot = lsum[0] + lsum[1] + lsum[2] + lsum[3];
        atomicAdd(loss_slot, tot * (3.0f / 3227648.0f));
    }
}

// ---------------------------------------------------------------------------
// Expand GEMM v2 (barrier-free): A = embf16[idx] gathered through LDS into
// AGPRs (64 rows x 256K); B = wet fragments direct from global (L2-hot).
// Block = 64 rows x 768 cols; wave w covers cols w*192 (12 tiles of 16).
__global__ __launch_bounds__(256, 2) void k_expand_mfma(const f16* __restrict__ embf16,
                                                        const int* __restrict__ idxp,
                                                        const f16* __restrict__ wet,
                                                        const float* __restrict__ be,
                                                        float* __restrict__ out)
{
    __shared__ __align__(16) f16 Abuf[64 * 256];  // 32 KB

    const int t = threadIdx.x;
    const int w = t >> 6, l = t & 63;
    const int m0 = blockIdx.x * 64;               // 198 blocks

    #pragma unroll
    for (int i = 0; i < 8; ++i) {
        int r = (w * 8 + i) * 2 + (l >> 5);
        int m = m0 + r; m = m < M_TOK ? m : (M_TOK - 1);
        int er = idxp[m];
        int c = (l & 31) ^ (r & 7);
        stage16(embf16 + (size_t)er * CD + c * 8, (char*)Abuf + (w * 8 + i) * 1024, l);
    }
    __syncthreads();
    f16x8 afr[4][8];
    #pragma unroll
    for (int mb = 0; mb < 4; ++mb) {
        int rl = mb * 16 + (l & 15);
        #pragma unroll
        for (int ks = 0; ks < 8; ++ks) {
            int pc = (ks * 4 + (l >> 4)) ^ (rl & 7);
            afr[mb][ks] = *(const f16x8*)((const char*)Abuf + rl * 512 + pc * 16);
        }
    }
    asm volatile("" ::: "memory");

    const int colw = w * 192;
    const f16* bpbase = wet + (size_t)(colw + (l & 15)) * CD + (l >> 4) * 8;
    f16x8 bf[8];
    #pragma unroll
    for (int ks = 0; ks < 8; ++ks) bf[ks] = *(const f16x8*)(bpbase + ks * 32);

    for (int jt = 0; jt < 12; ++jt) {
        f16x8 bfn[8];
        const f16* bpn = bpbase + (size_t)((jt + 1 < 12 ? jt + 1 : 0) * 16) * CD;
        #pragma unroll
        for (int ks = 0; ks < 8; ++ks) bfn[ks] = *(const f16x8*)(bpn + ks * 32);

        f32x4 acc[4];
        #pragma unroll
        for (int mb = 0; mb < 4; ++mb) acc[mb] = (f32x4){0.f,0.f,0.f,0.f};
        #pragma unroll
        for (int ks = 0; ks < 8; ++ks)
            #pragma unroll
            for (int mb = 0; mb < 4; ++mb)
                acc[mb] = __builtin_amdgcn_mfma_f32_16x16x32_f16(afr[mb][ks], bf[ks], acc[mb], 0, 0, 0);

        int col = colw + jt * 16 + (l & 15);
        float bev = be[col];
        #pragma unroll
        for (int mb = 0; mb < 4; ++mb) {
            #pragma unroll
            for (int reg = 0; reg < 4; ++reg) {
                int row = m0 + mb * 16 + (l >> 4) * 4 + reg;
                if (row < M_TOK)
                    out[(size_t)row * CIN + col] = acc[mb][reg] + bev;
            }
        }
        #pragma unroll
        for (int ks = 0; ks < 8; ++ks) bf[ks] = bfn[ks];
    }
}

// ---------------------------------------------------------------------------
// fp32 fallback compress (only if workspace too small for the split path)
#define BK1 16
__global__ __launch_bounds__(256) void k_compress(const float* __restrict__ z,
                                                  const float* __restrict__ W,
                                                  const float* __restrict__ bias,
                                                  float* __restrict__ zc,
                                                  f16* __restrict__ zcf16)
{
    __shared__ __align__(16) float As[BK1][64 + 4];
    __shared__ __align__(16) float Bs[BK1][64 + 4];
    const int t  = threadIdx.x;
    const int tx = t & 15, ty = t >> 4;
    const int row0 = blockIdx.x * 64;
    const int col0 = blockIdx.y * 64;

    const int la_r = t >> 2;
    const int la_k = (t & 3) << 2;
    const int lb_k = t >> 4;
    const int lb_n = (t & 15) << 2;

    float acc[4][4] = {};

    for (int k0 = 0; k0 < CIN; k0 += BK1) {
        float4 a4 = *(const float4*)&z[(size_t)(row0 + la_r) * CIN + k0 + la_k];
        float4 b4 = *(const float4*)&W[(size_t)(k0 + lb_k) * CD + col0 + lb_n];
        __syncthreads();
        As[la_k + 0][la_r] = a4.x; As[la_k + 1][la_r] = a4.y;
        As[la_k + 2][la_r] = a4.z; As[la_k + 3][la_r] = a4.w;
        *(float4*)&Bs[lb_k][lb_n] = b4;
        __syncthreads();
        #pragma unroll
        for (int k = 0; k < BK1; ++k) {
            float a[4], b[4];
            *(float4*)&a[0] = *(const float4*)&As[k][ty * 4];
            *(float4*)&b[0] = *(const float4*)&Bs[k][tx * 4];
            #pragma unroll
            for (int i = 0; i < 4; ++i)
                #pragma unroll
                for (int j = 0; j < 4; ++j)
                    acc[i][j] = fmaf(a[i], b[j], acc[i][j]);
        }
    }

    float4 bb = *(const float4*)&bias[col0 + tx * 4];
    #pragma unroll
    for (int i = 0; i < 4; ++i) {
        float4 v;
        v.x = acc[i][0] + bb.x; v.y = acc[i][1] + bb.y;
        v.z = acc[i][2] + bb.z; v.w = acc[i][3] + bb.w;
        size_t off = (size_t)(row0 + ty * 4 + i) * CD + col0 + tx * 4;
        *(float4*)&zc[off] = v;
        f16x4 hv = { (f16)v.x, (f16)v.y, (f16)v.z, (f16)v.w };
        *(f16x4*)&zcf16[off] = hv;
    }
}

// ---------------------------------------------------------------------------
extern "C" void kernel_launch(void* const* d_in, const int* in_sizes, int n_in,
                              void* d_out, int out_size, void* d_ws, size_t ws_size,
                              hipStream_t stream)
{
    (void)in_sizes; (void)n_in; (void)out_size;

    const float* z   = (const float*)d_in[0];
    const float* emb = (const float*)d_in[1];
    const float* Wc  = (const float*)d_in[2];
    const float* bc  = (const float*)d_in[3];
    const float* We  = (const float*)d_in[4];
    const float* be  = (const float*)d_in[5];

    float* out       = (float*)d_out;
    float* loss_slot = out + (size_t)M_TOK * CIN;

    char* base = (char*)d_ws;
    size_t off = 0;
    auto align_up = [](size_t x) { return (x + 255) & ~(size_t)255; };

    float* enorm = (float*)(base + off); off = align_up(off + (size_t)NE * 4);
    u64*   part  = (u64*)(base + off);   off = align_up(off + (size_t)M_TOK * 16 * 8);
    int*   idxp  = (int*)(base + off);   off = align_up(off + (size_t)M_TOK * 4);
    f16*   embf16= (f16*)(base + off);   off = align_up(off + (size_t)NE * CD * 2);
    f16*   zcf16 = (f16*)(base + off);   off = align_up(off + (size_t)MPAD * CD * 2);
    f16*   wet   = (f16*)(base + off);   off = align_up(off + (size_t)CIN * CD * 2);
    f16*   wchi  = (f16*)(base + off);   off = align_up(off + (size_t)CD * CIN * 2);
    f16*   wclo  = (f16*)(base + off);   off = align_up(off + (size_t)CD * CIN * 2);

    const size_t zsplit_bytes = (size_t)M_TOK * CIN * 2;
    bool have_split = (ws_size >= off + 2 * zsplit_bytes);
    f16 *zhi = nullptr, *zlo = nullptr;
    if (have_split) {
        zhi = (f16*)(base + off); off = align_up(off + zsplit_bytes);
        zlo = (f16*)(base + off); off = align_up(off + zsplit_bytes);
    }
    const size_t zc_bytes = (size_t)M_TOK * CD * 4;
    float* zc = (ws_size >= off + zc_bytes) ? (float*)(base + off) : out;

    if (have_split) {
        k_prep      <<<12272, 256, 0, stream>>>(emb, Wc, We, z, enorm, embf16,
                                                wchi, wclo, wet, zhi, zlo, loss_slot);
        k_compress_f<<<dim3(MPAD / 128, CD / 64), 256, 0, stream>>>(zhi, zlo, wchi, wclo,
                                                                    bc, zc, zcf16);
    } else {
        k_prep    <<<2816, 256, 0, stream>>>(emb, Wc, We, z, enorm, embf16,
                                             wchi, wclo, wet, (f16*)wchi, (f16*)wclo, loss_slot);
        k_compress<<<dim3(M_TOK / 64, CD / 64), 256, 0, stream>>>(z, Wc, bc, zc, zcf16);
    }

    k_dist_mfma  <<<dim3(MPAD / 64, NCHUNK), 256, 0, stream>>>(zcf16, embf16, enorm, part);
    k_rescore    <<<M_TOK / 4, 256, 0, stream>>>(zc, emb, enorm, part, idxp, loss_slot);
    k_expand_mfma<<<MPAD / 64, 256, 0, stream>>>(embf16, idxp, wet, be, out);
}

// Round 9
// 337.465 us; speedup vs baseline: 1.0321x; 1.0321x over previous
//
#include <hip/hip_runtime.h>
#include <stdint.h>

// Problem constants (B=64, N=197)
#define M_TOK 12608      // 64*197 tokens
#define MPAD  12672      // 198 * 64
#define CIN   768
#define CD    256
#define NE    8192
#define NCHUNK 8
#define CHUNK  1024

typedef unsigned long long u64;
typedef unsigned int u32;
typedef _Float16 f16;
typedef _Float16 f16x8 __attribute__((ext_vector_type(8)));
typedef _Float16 f16x4 __attribute__((ext_vector_type(4)));
typedef float f32x4 __attribute__((ext_vector_type(4)));

#if __has_builtin(__builtin_amdgcn_global_load_lds)
#define HAVE_GLL 1
#else
#define HAVE_GLL 0
#endif

// Stage one 16B chunk per lane into LDS. lds_base is wave-uniform; HW (or the
// fallback) adds lane*16.
__device__ __forceinline__ void stage16(const f16* src, char* lds_base, int lane)
{
#if HAVE_GLL
    __builtin_amdgcn_global_load_lds(
        (__attribute__((address_space(1))) void*)(src),
        (__attribute__((address_space(3))) void*)(lds_base), 16, 0, 0);
#else
    *(f16x8*)(lds_base + lane * 16) = *(const f16x8*)src;
#endif
}

// ---------------------------------------------------------------------------
// Fused prep: region A (2048 blocks): enorm + embf16 + loss zero.
// Region B (768 blocks): weight prep (WcT hi/lo split, WeT f16).
// Region C (9456 blocks): z -> zhi + zlo split.
__global__ __launch_bounds__(256) void k_prep(const float* __restrict__ emb,
                                              const float* __restrict__ Wc,
                                              const float* __restrict__ We,
                                              const float* __restrict__ z,
                                              float* __restrict__ enorm,
                                              f16* __restrict__ embf16,
                                              f16* __restrict__ wchi,
                                              f16* __restrict__ wclo,
                                              f16* __restrict__ wet,
                                              f16* __restrict__ zhi,
                                              f16* __restrict__ zlo,
                                              float* __restrict__ loss_slot)
{
    const int b = blockIdx.x;
    const int t = threadIdx.x;
    if (b < 2048) {
        if (b == 0 && t == 0) *loss_slot = 0.0f;
        int row  = b * 4 + (t >> 6);
        int lane = t & 63;
        float4 v = *(const float4*)&emb[(size_t)row * CD + lane * 4];
        f16x4 hv = { (f16)v.x, (f16)v.y, (f16)v.z, (f16)v.w };
        *(f16x4*)&embf16[(size_t)row * CD + lane * 4] = hv;
        float s = v.x*v.x + v.y*v.y + v.z*v.z + v.w*v.w;
        #pragma unroll
        for (int o = 32; o; o >>= 1) s += __shfl_down(s, o, 64);
        if (lane == 0) enorm[row] = s;
    } else if (b < 2048 + 768) {
        int tid = (b - 2048) * 256 + t;            // < 196608
        {
            int n = tid & 255, k = tid >> 8;
            float v = Wc[(size_t)k * CD + n];
            f16 h = (f16)v;
            wchi[(size_t)n * CIN + k] = h;
            wclo[(size_t)n * CIN + k] = (f16)(v - (float)h);
        }
        {
            int d = tid / CIN, c = tid - d * CIN;
            wet[(size_t)c * CD + d] = (f16)We[(size_t)d * CIN + c];
        }
    } else {
        size_t i4 = (size_t)(b - 2816) * 256 + t;  // float4 idx, 2420736 total
        float4 v = ((const float4*)z)[i4];
        f16x4 h = { (f16)v.x, (f16)v.y, (f16)v.z, (f16)v.w };
        f16x4 lo = { (f16)(v.x - (float)h.x), (f16)(v.y - (float)h.y),
                     (f16)(v.z - (float)h.z), (f16)(v.w - (float)h.w) };
        ((f16x4*)zhi)[i4] = h;
        ((f16x4*)zlo)[i4] = lo;
    }
}

// ---------------------------------------------------------------------------
// Fused split-f16 compress: zc = zhi@WhiT + zhi@WloT + zlo@WhiT + bc, writes
// zc (f32) and zcf16. 128x64 tile, BK=64, K=768.
__global__ __launch_bounds__(256) void k_compress_f(const f16* __restrict__ zhi,
                                                    const f16* __restrict__ zlo,
                                                    const f16* __restrict__ wchi,
                                                    const f16* __restrict__ wclo,
                                                    const float* __restrict__ bc,
                                                    float* __restrict__ zc,
                                                    f16* __restrict__ zcf16)
{
    __shared__ __align__(16) f16 Ah[128 * 64];   // 16 KB
    __shared__ __align__(16) f16 Al[128 * 64];   // 16 KB
    __shared__ __align__(16) f16 Bh[64 * 64];    // 8 KB
    __shared__ __align__(16) f16 Bl[64 * 64];    // 8 KB

    const int t = threadIdx.x;
    const int w = t >> 6, l = t & 63;
    const int wrow = w * 32;
    const int m0   = blockIdx.x * 128;
    const int col0 = blockIdx.y * 64;

    const int cg   = (t & 7) ^ ((t >> 3) & 7);
    const int rloc = t >> 3;
    const f16* ahsrc[4]; const f16* alsrc[4];
    #pragma unroll
    for (int i = 0; i < 4; ++i) {
        int am = m0 + i * 32 + rloc; am = am < M_TOK ? am : (M_TOK - 1);
        ahsrc[i] = zhi + (size_t)am * CIN + cg * 8;
        alsrc[i] = zlo + (size_t)am * CIN + cg * 8;
    }
    const f16* bhsrc[2]; const f16* blsrc[2];
    #pragma unroll
    for (int i = 0; i < 2; ++i) {
        int br = col0 + i * 32 + rloc;
        bhsrc[i] = wchi + (size_t)br * CIN + cg * 8;
        blsrc[i] = wclo + (size_t)br * CIN + cg * 8;
    }

    f32x4 acc[2][4];
    #pragma unroll
    for (int a = 0; a < 2; ++a)
        #pragma unroll
        for (int b2 = 0; b2 < 4; ++b2) acc[a][b2] = (f32x4){0.f,0.f,0.f,0.f};

    for (int ks = 0; ks < CIN / 64; ++ks) {
        __syncthreads();
        #pragma unroll
        for (int i = 0; i < 4; ++i) {
            stage16(ahsrc[i] + ks * 64, (char*)Ah + (i * 256 + w * 64) * 16, l);
            stage16(alsrc[i] + ks * 64, (char*)Al + (i * 256 + w * 64) * 16, l);
        }
        #pragma unroll
        for (int i = 0; i < 2; ++i) {
            stage16(bhsrc[i] + ks * 64, (char*)Bh + (i * 256 + w * 64) * 16, l);
            stage16(blsrc[i] + ks * 64, (char*)Bl + (i * 256 + w * 64) * 16, l);
        }
        __syncthreads();
        #pragma unroll
        for (int kk = 0; kk < 2; ++kk) {
            const int pofs = ((kk * 4 + (l >> 4)) ^ (l & 7)) * 16;
            f16x8 ah[2], al[2], bh[4], bl[4];
            #pragma unroll
            for (int tm = 0; tm < 2; ++tm) {
                ah[tm] = *(const f16x8*)((const char*)Ah + (wrow + tm*16 + (l & 15)) * 128 + pofs);
                al[tm] = *(const f16x8*)((const char*)Al + (wrow + tm*16 + (l & 15)) * 128 + pofs);
            }
            #pragma unroll
            for (int tn = 0; tn < 4; ++tn) {
                bh[tn] = *(const f16x8*)((const char*)Bh + (tn*16 + (l & 15)) * 128 + pofs);
                bl[tn] = *(const f16x8*)((const char*)Bl + (tn*16 + (l & 15)) * 128 + pofs);
            }
            #pragma unroll
            for (int tm = 0; tm < 2; ++tm)
                #pragma unroll
                for (int tn = 0; tn < 4; ++tn) {
                    f32x4 a = acc[tm][tn];
                    a = __builtin_amdgcn_mfma_f32_16x16x32_f16(ah[tm], bh[tn], a, 0, 0, 0);
                    a = __builtin_amdgcn_mfma_f32_16x16x32_f16(ah[tm], bl[tn], a, 0, 0, 0);
                    a = __builtin_amdgcn_mfma_f32_16x16x32_f16(al[tm], bh[tn], a, 0, 0, 0);
                    acc[tm][tn] = a;
                }
        }
    }

    #pragma unroll
    for (int tm = 0; tm < 2; ++tm) {
        #pragma unroll
        for (int reg = 0; reg < 4; ++reg) {
            int row = m0 + wrow + tm * 16 + (l >> 4) * 4 + reg;
            if (row < M_TOK) {
                #pragma unroll
                for (int tn = 0; tn < 4; ++tn) {
                    int col = col0 + tn * 16 + (l & 15);
                    float v = acc[tm][tn][reg] + bc[col];
                    zc[(size_t)row * CD + col] = v;
                    zcf16[(size_t)row * CD + col] = (f16)v;
                }
            }
        }
    }
}

// ---------------------------------------------------------------------------
// Coarse distance GEMM v6: barrier-free j-loop; A bounced global->LDS->regs
// with VOLATILE extraction loads (cannot be re-executed/rematerialized ->
// afr[4][8] must stay register-resident; spill would show in WRITE_SIZE).
// B fragments direct from global (L2-hot), one-tile prefetch.
__global__ __launch_bounds__(256, 2) void k_dist_mfma(const f16* __restrict__ zcf16,
                                                      const f16* __restrict__ embf16,
                                                      const float* __restrict__ enorm,
                                                      u64* __restrict__ part)
{
    __shared__ __align__(16) f16 Abuf[64 * 256];  // 32 KB bounce buffer
    __shared__ u64 wred[64][4][2];                // 4 KB

    const int t = threadIdx.x;
    const int w = t >> 6, l = t & 63;
    const int m0    = blockIdx.x * 64;            // 198 m-blocks
    const int chunk = blockIdx.y;                 // 0..7
    const int jb    = chunk * CHUNK + w * 256;    // wave's 256-col range

    // ---- stage A (swizzled) and extract to registers ----
    #pragma unroll
    for (int i = 0; i < 8; ++i) {
        int r = (w * 8 + i) * 2 + (l >> 5);
        int c = (l & 31) ^ (r & 7);
        int gr = m0 + r; gr = gr < M_TOK ? gr : (M_TOK - 1);
        stage16(zcf16 + (size_t)gr * CD + c * 8, (char*)Abuf + (w * 8 + i) * 1024, l);
    }
    __syncthreads();
    f16x8 afr[4][8];
    #pragma unroll
    for (int mb = 0; mb < 4; ++mb) {
        int rl = mb * 16 + (l & 15);
        #pragma unroll
        for (int ks = 0; ks < 8; ++ks) {
            int pc = (ks * 4 + (l >> 4)) ^ (rl & 7);
            afr[mb][ks] = *(volatile const f16x8*)((const char*)Abuf + rl * 512 + pc * 16);
        }
    }

    float bd[16];
    #pragma unroll
    for (int s = 0; s < 16; ++s) bd[s] = __builtin_inff();

    // ---- barrier-free j-loop: 16 tiles of 16 cols, B direct from global ----
    const f16* bpbase = embf16 + (size_t)(jb + (l & 15)) * CD + (l >> 4) * 8;
    f16x8 bf[8];
    #pragma unroll
    for (int ks = 0; ks < 8; ++ks) bf[ks] = *(const f16x8*)(bpbase + ks * 32);

    for (int jt = 0; jt < 16; ++jt) {
        // prefetch next tile's fragments (wraps harmlessly at the end)
        f16x8 bfn[8];
        const f16* bpn = bpbase + (size_t)(((jt + 1) & 15) * 16) * CD;
        #pragma unroll
        for (int ks = 0; ks < 8; ++ks) bfn[ks] = *(const f16x8*)(bpn + ks * 32);

        f32x4 acc[4];
        #pragma unroll
        for (int mb = 0; mb < 4; ++mb) acc[mb] = (f32x4){0.f,0.f,0.f,0.f};
        #pragma unroll
        for (int ks = 0; ks < 8; ++ks)
            #pragma unroll
            for (int mb = 0; mb < 4; ++mb)
                acc[mb] = __builtin_amdgcn_mfma_f32_16x16x32_f16(afr[mb][ks], bf[ks], acc[mb], 0, 0, 0);

        float en = enorm[jb + jt * 16 + (l & 15)];
        #pragma unroll
        for (int mb = 0; mb < 4; ++mb) {
            #pragma unroll
            for (int reg = 0; reg < 4; ++reg) {
                float d = fmaf(acc[mb][reg], -2.f, en);
                float ds = __uint_as_float((__float_as_uint(d) & ~15u) | (u32)jt);
                float cur = bd[mb * 4 + reg];
                bd[mb * 4 + reg] = ds < cur ? ds : cur;
            }
        }
        #pragma unroll
        for (int ks = 0; ks < 8; ++ks) bf[ks] = bfn[ks];
    }

    // ---- per-row top-2 across the 16 col-lanes, merge 4 waves in LDS ----
    #pragma unroll
    for (int mb = 0; mb < 4; ++mb) {
        #pragma unroll
        for (int reg = 0; reg < 4; ++reg) {
            u32 bits = __float_as_uint(bd[mb * 4 + reg]);
            int jtb  = (int)(bits & 15u);
            int col  = jb + jtb * 16 + (l & 15);
            u32 u = (bits & 0x80000000u) ? ~bits : (bits | 0x80000000u);
            u64 b  = ((u64)u << 32) | (u32)col;
            u64 s2 = ~0ull;
            #pragma unroll
            for (int off = 1; off <= 8; off <<= 1) {
                u64 ob = __shfl_xor(b, off, 64);
                u64 os = __shfl_xor(s2, off, 64);
                u64 nb = b < ob ? b : ob;
                u64 mx = b < ob ? ob : b;
                s2 = s2 < os ? s2 : os;
                s2 = s2 < mx ? s2 : mx;
                b = nb;
            }
            if ((l & 15) == 0) {
                int row = mb * 16 + (l >> 4) * 4 + reg;
                wred[row][w][0] = b;
                wred[row][w][1] = s2;
            }
        }
    }
    __syncthreads();
    if (t < 64) {
        u64 best = wred[t][0][0], sec = wred[t][0][1];
        #pragma unroll
        for (int c = 1; c < 4; ++c) {
            u64 b = wred[t][c][0], s = wred[t][c][1];
            if (b < best) { sec = (best < s) ? best : s; best = b; }
            else if (b < sec) { sec = b; }
        }
        int row = m0 + t;
        if (row < M_TOK) {
            part[((size_t)row * NCHUNK + chunk) * 2 + 0] = best;
            part[((size_t)row * NCHUNK + chunk) * 2 + 1] = sec;
        }
    }
}

// ---------------------------------------------------------------------------
// Exact fp32 rescore of the 4 coarsely-best of the 16 candidates (keys are
// globally comparable). FIXED selection: one wave-wide ballot per target rank
// (lane-uniform predicate target), lane picks its mask by slot s = l&3.
__global__ __launch_bounds__(256) void k_rescore(const float* __restrict__ zc,
                                                 const float* __restrict__ emb,
                                                 const float* __restrict__ enorm,
                                                 const u64* __restrict__ part,
                                                 int* __restrict__ idxp,
                                                 float* __restrict__ loss_slot)
{
    const int row = blockIdx.x * 4 + (threadIdx.x >> 6);   // grid 3152 -> exactly M_TOK
    const int l   = threadIdx.x & 63;
    __shared__ float lsum[4];

    // rank the 16 keys (replicated across the 4 sixteen-lane groups)
    u64 key = part[(size_t)row * 16 + (l & 15)];
    int cnt = 0;
    #pragma unroll
    for (int j = 0; j < 16; ++j) {
        u64 kj = __shfl(key, (l & 48) | j, 64);
        cnt += (kj < key) ? 1 : 0;
    }
    int mycol = (int)((u32)key & (NE - 1));
    // one ballot per target rank (predicate target is lane-uniform)
    unsigned long long r0 = __ballot(cnt == 0);
    unsigned long long r1 = __ballot(cnt == 1);
    unsigned long long r2 = __ballot(cnt == 2);
    unsigned long long r3 = __ballot(cnt == 3);
    const int s = l & 3;
    unsigned long long msel = (s == 0) ? r0 : (s == 1) ? r1 : (s == 2) ? r2 : r3;
    int base = l & 48;
    unsigned long long gm = (msel >> base) & 0xFFFFull;
    int col = __shfl(mycol, base + (int)__builtin_ctzll(gm), 64);

    const int q = l >> 2;                 // 16 K-chunks of 16 floats
    const float4* ep = (const float4*)emb + (size_t)col * 64 + q * 4;
    const float4* zp = (const float4*)zc  + (size_t)row * 64 + q * 4;
    float p = 0.f, zn = 0.f;
    #pragma unroll
    for (int i = 0; i < 4; ++i) {
        float4 e = ep[i], zv = zp[i];
        p  = fmaf(e.x, zv.x, fmaf(e.y, zv.y, fmaf(e.z, zv.z, fmaf(e.w, zv.w, p))));
        zn = fmaf(zv.x, zv.x, fmaf(zv.y, zv.y, fmaf(zv.z, zv.z, fmaf(zv.w, zv.w, zn))));
    }
    // reduce over the 16 lanes sharing a slot (stride-4 lanes)
    p  += __shfl_xor(p, 4, 64);  p  += __shfl_xor(p, 8, 64);
    p  += __shfl_xor(p, 16, 64); p  += __shfl_xor(p, 32, 64);
    zn += __shfl_xor(zn, 4, 64); zn += __shfl_xor(zn, 8, 64);
    zn += __shfl_xor(zn, 16, 64); zn += __shfl_xor(zn, 32, 64);

    float d = fmaf(p, -2.f, enorm[col]);
    u32 u = __float_as_uint(d);
    u = (u & 0x80000000u) ? ~u : (u | 0x80000000u);
    u64 best = ((u64)u << 32) | (u32)col;
    u64 ob;
    ob = __shfl_xor(best, 1, 64); best = ob < best ? ob : best;
    ob = __shfl_xor(best, 2, 64); best = ob < best ? ob : best;

    u32 hi = (u32)(best >> 32);
    float dbest = (hi & 0x80000000u) ? __uint_as_float(hi & 0x7fffffffu)
                                     : __uint_as_float(~hi);
    if (l == 0) {
        idxp[row] = (int)((u32)best & (NE - 1));
        lsum[threadIdx.x >> 6] = dbest + zn;
    }
    __syncthreads();
    if (threadIdx.x == 0) {
        float tot = lsum[0] + lsum[1] + lsum[2] + lsum[3];
        atomicAdd(loss_slot, tot * (3.0f / 3227648.0f));
    }
}

// ---------------------------------------------------------------------------
// Expand GEMM v3 (barrier-free): A = embf16[idx] gathered via LDS into regs
// (volatile-pinned); B = wet fragments direct from global (L2-hot).
// Grid (198, 2): block = 64 rows x 384 cols; wave w covers 96 cols (6 tiles).
__global__ __launch_bounds__(256, 2) void k_expand_mfma(const f16* __restrict__ embf16,
                                                        const int* __restrict__ idxp,
                                                        const f16* __restrict__ wet,
                                                        const float* __restrict__ be,
                                                        float* __restrict__ out)
{
    __shared__ __align__(16) f16 Abuf[64 * 256];  // 32 KB

    const int t = threadIdx.x;
    const int w = t >> 6, l = t & 63;
    const int m0 = blockIdx.x * 64;               // 198

    #pragma unroll
    for (int i = 0; i < 8; ++i) {
        int r = (w * 8 + i) * 2 + (l >> 5);
        int mm = m0 + r; mm = mm < M_TOK ? mm : (M_TOK - 1);
        int er = idxp[mm];
        int c = (l & 31) ^ (r & 7);
        stage16(embf16 + (size_t)er * CD + c * 8, (char*)Abuf + (w * 8 + i) * 1024, l);
    }
    __syncthreads();
    f16x8 afr[4][8];
    #pragma unroll
    for (int mb = 0; mb < 4; ++mb) {
        int rl = mb * 16 + (l & 15);
        #pragma unroll
        for (int ks = 0; ks < 8; ++ks) {
            int pc = (ks * 4 + (l >> 4)) ^ (rl & 7);
            afr[mb][ks] = *(volatile const f16x8*)((const char*)Abuf + rl * 512 + pc * 16);
        }
    }

    const int colw = blockIdx.y * 384 + w * 96;
    const f16* bpbase = wet + (size_t)(colw + (l & 15)) * CD + (l >> 4) * 8;
    f16x8 bf[8];
    #pragma unroll
    for (int ks = 0; ks < 8; ++ks) bf[ks] = *(const f16x8*)(bpbase + ks * 32);

    for (int jt = 0; jt < 6; ++jt) {
        f16x8 bfn[8];
        const f16* bpn = bpbase + (size_t)((jt + 1 < 6 ? jt + 1 : 0) * 16) * CD;
        #pragma unroll
        for (int ks = 0; ks < 8; ++ks) bfn[ks] = *(const f16x8*)(bpn + ks * 32);

        f32x4 acc[4];
        #pragma unroll
        for (int mb = 0; mb < 4; ++mb) acc[mb] = (f32x4){0.f,0.f,0.f,0.f};
        #pragma unroll
        for (int ks = 0; ks < 8; ++ks)
            #pragma unroll
            for (int mb = 0; mb < 4; ++mb)
                acc[mb] = __builtin_amdgcn_mfma_f32_16x16x32_f16(afr[mb][ks], bf[ks], acc[mb], 0, 0, 0);

        int col = colw + jt * 16 + (l & 15);
        float bev = be[col];
        #pragma unroll
        for (int mb = 0; mb < 4; ++mb) {
            #pragma unroll
            for (int reg = 0; reg < 4; ++reg) {
                int row = m0 + mb * 16 + (l >> 4) * 4 + reg;
                if (row < M_TOK)
                    out[(size_t)row * CIN + col] = acc[mb][reg] + bev;
            }
        }
        #pragma unroll
        for (int ks = 0; ks < 8; ++ks) bf[ks] = bfn[ks];
    }
}

// ---------------------------------------------------------------------------
// fp32 fallback compress (only if workspace too small for the split path)
#define BK1 16
__global__ __launch_bounds__(256) void k_compress(const float* __restrict__ z,
                                                  const float* __restrict__ W,
                                                  const float* __restrict__ bias,
                                                  float* __restrict__ zc,
                                                  f16* __restrict__ zcf16)
{
    __shared__ __align__(16) float As[BK1][64 + 4];
    __shared__ __align__(16) float Bs[BK1][64 + 4];
    const int t  = threadIdx.x;
    const int tx = t & 15, ty = t >> 4;
    const int row0 = blockIdx.x * 64;
    const int col0 = blockIdx.y * 64;

    const int la_r = t >> 2;
    const int la_k = (t & 3) << 2;
    const int lb_k = t >> 4;
    const int lb_n = (t & 15) << 2;

    float acc[4][4] = {};

    for (int k0 = 0; k0 < CIN; k0 += BK1) {
        float4 a4 = *(const float4*)&z[(size_t)(row0 + la_r) * CIN + k0 + la_k];
        float4 b4 = *(const float4*)&W[(size_t)(k0 + lb_k) * CD + col0 + lb_n];
        __syncthreads();
        As[la_k + 0][la_r] = a4.x; As[la_k + 1][la_r] = a4.y;
        As[la_k + 2][la_r] = a4.z; As[la_k + 3][la_r] = a4.w;
        *(float4*)&Bs[lb_k][lb_n] = b4;
        __syncthreads();
        #pragma unroll
        for (int k = 0; k < BK1; ++k) {
            float a[4], b[4];
            *(float4*)&a[0] = *(const float4*)&As[k][ty * 4];
            *(float4*)&b[0] = *(const float4*)&Bs[k][tx * 4];
            #pragma unroll
            for (int i = 0; i < 4; ++i)
                #pragma unroll
                for (int j = 0; j < 4; ++j)
                    acc[i][j] = fmaf(a[i], b[j], acc[i][j]);
        }
    }

    float4 bb = *(const float4*)&bias[col0 + tx * 4];
    #pragma unroll
    for (int i = 0; i < 4; ++i) {
        float4 v;
        v.x = acc[i][0] + bb.x; v.y = acc[i][1] + bb.y;
        v.z = acc[i][2] + bb.z; v.w = acc[i][3] + bb.w;
        size_t off = (size_t)(row0 + ty * 4 + i) * CD + col0 + tx * 4;
        *(float4*)&zc[off] = v;
        f16x4 hv = { (f16)v.x, (f16)v.y, (f16)v.z, (f16)v.w };
        *(f16x4*)&zcf16[off] = hv;
    }
}

// ---------------------------------------------------------------------------
extern "C" void kernel_launch(void* const* d_in, const int* in_sizes, int n_in,
                              void* d_out, int out_size, void* d_ws, size_t ws_size,
                              hipStream_t stream)
{
    (void)in_sizes; (void)n_in; (void)out_size;

    const float* z   = (const float*)d_in[0];
    const float* emb = (const float*)d_in[1];
    const float* Wc  = (const float*)d_in[2];
    const float* bc  = (const float*)d_in[3];
    const float* We  = (const float*)d_in[4];
    const float* be  = (const float*)d_in[5];

    float* out       = (float*)d_out;
    float* loss_slot = out + (size_t)M_TOK * CIN;

    char* base = (char*)d_ws;
    size_t off = 0;
    auto align_up = [](size_t x) { return (x + 255) & ~(size_t)255; };

    float* enorm = (float*)(base + off); off = align_up(off + (size_t)NE * 4);
    u64*   part  = (u64*)(base + off);   off = align_up(off + (size_t)M_TOK * 16 * 8);
    int*   idxp  = (int*)(base + off);   off = align_up(off + (size_t)M_TOK * 4);
    f16*   embf16= (f16*)(base + off);   off = align_up(off + (size_t)NE * CD * 2);
    f16*   zcf16 = (f16*)(base + off);   off = align_up(off + (size_t)MPAD * CD * 2);
    f16*   wet   = (f16*)(base + off);   off = align_up(off + (size_t)CIN * CD * 2);
    f16*   wchi  = (f16*)(base + off);   off = align_up(off + (size_t)CD * CIN * 2);
    f16*   wclo  = (f16*)(base + off);   off = align_up(off + (size_t)CD * CIN * 2);

    const size_t zsplit_bytes = (size_t)M_TOK * CIN * 2;
    bool have_split = (ws_size >= off + 2 * zsplit_bytes);
    f16 *zhi = nullptr, *zlo = nullptr;
    if (have_split) {
        zhi = (f16*)(base + off); off = align_up(off + zsplit_bytes);
        zlo = (f16*)(base + off); off = align_up(off + zsplit_bytes);
    }
    const size_t zc_bytes = (size_t)M_TOK * CD * 4;
    float* zc = (ws_size >= off + zc_bytes) ? (float*)(base + off) : out;

    if (have_split) {
        k_prep      <<<12272, 256, 0, stream>>>(emb, Wc, We, z, enorm, embf16,
                                                wchi, wclo, wet, zhi, zlo, loss_slot);
        k_compress_f<<<dim3(MPAD / 128, CD / 64), 256, 0, stream>>>(zhi, zlo, wchi, wclo,
                                                                    bc, zc, zcf16);
    } else {
        k_prep    <<<2816, 256, 0, stream>>>(emb, Wc, We, z, enorm, embf16,
                                             wchi, wclo, wet, (f16*)wchi, (f16*)wclo, loss_slot);
        k_compress<<<dim3(M_TOK / 64, CD / 64), 256, 0, stream>>>(z, Wc, bc, zc, zcf16);
    }

    k_dist_mfma  <<<dim3(MPAD / 64, NCHUNK), 256, 0, stream>>>(zcf16, embf16, enorm, part);
    k_rescore    <<<M_TOK / 4, 256, 0, stream>>>(zc, emb, enorm, part, idxp, loss_slot);
    k_expand_mfma<<<dim3(MPAD / 64, 2), 256, 0, stream>>>(embf16, idxp, wet, be, out);
}